// Round 4
// baseline (637.667 us; speedup 1.0000x reference)
//
#include <hip/hip_runtime.h>

#define RANK 256
#define NB 8192
#define NMAP 15625

// workspace byte offsets (total ~8.5 MB)
#define GE_OFF    0          // 8192*256 f32 = 8,388,608 B
#define INV_OFF   8388608    // 15625 int   = 62,500 B
#define PARTS_OFF 8451120    // 32*256 f32  = 32,768 B (16-aligned)
#define C2_OFF    8483888    // 256 f32

// ---------------------------------------------------------------- inv = -1
__global__ void k_init_inv(int* inv) {
    int i = blockIdx.x * 256 + threadIdx.x;
    if (i < NMAP) inv[i] = -1;
}

// ------------------------------------------------- inv[key_idx[b]] = b
__global__ void k_scatter(const int* key_ids, int* inv) {
    int b = blockIdx.x * 256 + threadIdx.x;   // 32 blocks x 256 = 8192
    const int* kp = key_ids + b * 6;
    int k = kp[0]*3125 + kp[1]*625 + kp[2]*125 + kp[3]*25 + kp[4]*5 + kp[5];
    inv[k] = b;
}

// ---------------- fused GraphReader: embed + 3x(SAGE->fc->LN->ReLU) --------
// block = 256 threads = 2 graphs; thread: graph g = tid>>7, cols 2c, 2c+1
__global__ void k_graph_reader(const int* __restrict__ features,
                               const float* __restrict__ emb,
                               const float* __restrict__ sageW,
                               const float* __restrict__ sageB,
                               const float* __restrict__ lnG,
                               const float* __restrict__ lnB,
                               float* __restrict__ GE)
{
    __shared__ __align__(16) float sX[18 * RANK];   // activations, 18 KB
    __shared__ __align__(16) float sA[18 * RANK];   // aggregates,  18 KB
    __shared__ float sMV[18 * 2];
    __shared__ int   sFeat[18];

    const int tid = threadIdx.x;
    const int g   = tid >> 7;       // 0..1
    const int c   = tid & 127;      // cols 2c, 2c+1
    const int b0  = blockIdx.x * 2;

    if (tid < 18) sFeat[tid] = features[b0 * 9 + tid];
    __syncthreads();

    // embed fill: 18 rows x 64 float4 chunks = 1152 tasks
    for (int it = 0; it < 5; ++it) {
        int t = tid + it * 256;
        if (t < 1152) {
            int row = t >> 6, c4 = t & 63;
            *(float4*)(sX + row * RANK + c4 * 4) =
                *(const float4*)(emb + sFeat[row] * RANK + c4 * 4);
        }
    }

    for (int L = 0; L < 3; ++L) {
        __syncthreads();   // sX ready (embed or previous layer write-back)

        // chain aggregation: (x[r-1]+x[r]+x[r+1]) / (deg+1), fp32
        for (int it = 0; it < 5; ++it) {
            int t = tid + it * 256;
            if (t < 1152) {
                int row = t >> 6, c4 = t & 63;
                int r = row - (row / 9) * 9;
                float4 v = *(const float4*)(sX + row * RANK + c4 * 4);
                float cnt = 1.f;
                if (r > 0) {
                    float4 u = *(const float4*)(sX + (row - 1) * RANK + c4 * 4);
                    v.x += u.x; v.y += u.y; v.z += u.z; v.w += u.w; cnt += 1.f;
                }
                if (r < 8) {
                    float4 u = *(const float4*)(sX + (row + 1) * RANK + c4 * 4);
                    v.x += u.x; v.y += u.y; v.z += u.z; v.w += u.w; cnt += 1.f;
                }
                float sc = 1.0f / cnt;
                v.x *= sc; v.y *= sc; v.z *= sc; v.w *= sc;
                *(float4*)(sA + row * RANK + c4 * 4) = v;
            }
        }
        __syncthreads();   // sA ready

        // GEMV: y[9][2] = A[9][256] @ W[256][2 cols] + bias
        float y[9][2];
        {
            const float* bp = sageB + L * RANK + c * 2;
            float v0 = bp[0], v1 = bp[1];
            #pragma unroll
            for (int r = 0; r < 9; ++r) { y[r][0] = v0; y[r][1] = v1; }
        }
        const float* Wp = sageW + L * RANK * RANK;
        const float* Ap = sA + g * 9 * RANK;
        for (int k0 = 0; k0 < RANK; k0 += 4) {
            float w00, w01, w10, w11, w20, w21, w30, w31;
            {
                float2 t0 = *(const float2*)(Wp + (k0    ) * RANK + c * 2);
                float2 t1 = *(const float2*)(Wp + (k0 + 1) * RANK + c * 2);
                float2 t2 = *(const float2*)(Wp + (k0 + 2) * RANK + c * 2);
                float2 t3 = *(const float2*)(Wp + (k0 + 3) * RANK + c * 2);
                w00 = t0.x; w01 = t0.y; w10 = t1.x; w11 = t1.y;
                w20 = t2.x; w21 = t2.y; w30 = t3.x; w31 = t3.y;
            }
            #pragma unroll
            for (int r = 0; r < 9; ++r) {
                float4 a = *(const float4*)(Ap + r * RANK + k0);
                y[r][0] += a.x * w00 + a.y * w10 + a.z * w20 + a.w * w30;
                y[r][1] += a.x * w01 + a.y * w11 + a.z * w21 + a.w * w31;
            }
        }

        __syncthreads();   // done reading sA -> reuse as LN scratch
        float* sRs = sA;            // [18][128] sums
        float* sRq = sA + 2304;     // [18][128] sq-sums
        #pragma unroll
        for (int r = 0; r < 9; ++r) {
            sRs[(g * 9 + r) * 128 + c] = y[r][0] + y[r][1];
            sRq[(g * 9 + r) * 128 + c] = y[r][0] * y[r][0] + y[r][1] * y[r][1];
        }
        __syncthreads();
        if (tid < 18) {
            float s = 0.f, q = 0.f;
            for (int i = 0; i < 128; ++i) { s += sRs[tid * 128 + i]; q += sRq[tid * 128 + i]; }
            float m = s * (1.0f / 256.0f);
            float var = q * (1.0f / 256.0f) - m * m;
            if (var < 0.f) var = 0.f;
            sMV[tid * 2]     = m;
            sMV[tid * 2 + 1] = rsqrtf(var + 1e-5f);
        }
        __syncthreads();

        // normalize + ReLU + write back (GE on last layer, node 0 only)
        const float* gp  = lnG + L * RANK + c * 2;
        const float* bp2 = lnB + L * RANK + c * 2;
        float g0 = gp[0], g1 = gp[1], bb0 = bp2[0], bb1 = bp2[1];
        #pragma unroll
        for (int r = 0; r < 9; ++r) {
            float m  = sMV[(g * 9 + r) * 2];
            float rs = sMV[(g * 9 + r) * 2 + 1];
            float v0 = (y[r][0] - m) * rs * g0 + bb0;
            float v1 = (y[r][1] - m) * rs * g1 + bb1;
            if (v0 < 0.f) v0 = 0.f;
            if (v1 < 0.f) v1 = 0.f;
            if (L < 2) {
                sX[(g * 9 + r) * RANK + c * 2]     = v0;
                sX[(g * 9 + r) * RANK + c * 2 + 1] = v1;
            } else if (r == 0) {
                GE[(b0 + g) * RANK + c * 2]     = v0;
                GE[(b0 + g) * RANK + c * 2 + 1] = v1;
            }
        }
    }
}

// ---------------- dd aggregation partials (deterministic) ------------------
__global__ void k_dd_agg(const int* __restrict__ dd_src,
                         const int* __restrict__ inv,
                         const float* __restrict__ GE,
                         float* __restrict__ parts)
{
    const int c  = threadIdx.x;
    const int e0 = blockIdx.x * 64;
    float s = 0.f;
    for (int e = e0; e < e0 + 64; ++e) {
        int b = inv[dd_src[e]];
        if (b >= 0) s += GE[b * RANK + c];
    }
    parts[blockIdx.x * RANK + c] = s;
}

// ---------------- device-node vector path -> c2 ----------------------------
__global__ void k_device(const float* __restrict__ parts,
                         const float* __restrict__ aug,
                         const float* __restrict__ infoW,
                         const float* __restrict__ infoB,
                         const float* __restrict__ ddW,
                         const float* __restrict__ ddB,
                         const float* __restrict__ normG,
                         const float* __restrict__ normB,
                         const float* __restrict__ predW1,
                         const float* __restrict__ predB1,
                         float* __restrict__ c2)
{
    __shared__ float sh[RANK];
    __shared__ float sdev[RANK];
    __shared__ float sred[RANK];
    const int n = threadIdx.x;

    float agg = 0.f;
    for (int p = 0; p < 32; ++p) agg += parts[p * RANK + n];
    float info = infoB[n];
    for (int j = 0; j < 5; ++j) info += aug[j] * infoW[j * RANK + n];
    sh[n] = (agg + info) * (1.0f / 2049.0f);   // (agg + self) / (deg + 1)
    __syncthreads();

    float y = ddB[n];
    for (int k = 0; k < RANK; ++k) y += sh[k] * ddW[k * RANK + n];

    sred[n] = y; __syncthreads();
    for (int off = 128; off > 0; off >>= 1) {
        if (n < off) sred[n] += sred[n + off];
        __syncthreads();
    }
    float s = sred[0]; __syncthreads();
    sred[n] = y * y; __syncthreads();
    for (int off = 128; off > 0; off >>= 1) {
        if (n < off) sred[n] += sred[n + off];
        __syncthreads();
    }
    float q = sred[0]; __syncthreads();

    float m = s * (1.0f / 256.0f);
    float var = q * (1.0f / 256.0f) - m * m;
    if (var < 0.f) var = 0.f;
    float rs = rsqrtf(var + 1e-5f);
    float dev = (y - m) * rs * normG[n] + normB[n];
    if (dev < 0.f) dev = 0.f;
    sdev[n] = dev;
    __syncthreads();

    float o = predB1[n];
    for (int k = 0; k < RANK; ++k) o += sdev[k] * predW1[(RANK + k) * RANK + n];
    c2[n] = o;
}

// ---------------- final: out = relu(GE @ W1a + c2) . W2 + b2 ---------------
// block = 256 threads = 16 output rows; thread owns col n = tid
__global__ void k_pred(const float* __restrict__ GE,
                       const float* __restrict__ predW1,
                       const float* __restrict__ c2,
                       const float* __restrict__ predW2,
                       const float* __restrict__ predB2,
                       float* __restrict__ out)
{
    __shared__ __align__(16) float sG[16 * RANK];   // 16 KB
    __shared__ float sRed[16 * RANK];               // 16 KB
    __shared__ float sQ[256];
    const int tid = threadIdx.x;
    const int m0  = blockIdx.x * 16;

    for (int it = 0; it < 4; ++it) {
        int t = tid + it * 256;     // 16 rows x 64 float4 chunks
        int r = t >> 6, c4 = t & 63;
        *(float4*)(sG + r * RANK + c4 * 4) = *(const float4*)(GE + (m0 + r) * RANK + c4 * 4);
    }
    __syncthreads();

    const int n = tid;
    float y[16];
    #pragma unroll
    for (int r = 0; r < 16; ++r) y[r] = 0.f;
    for (int k0 = 0; k0 < RANK; k0 += 2) {
        float w0 = predW1[k0 * RANK + n];
        float w1 = predW1[(k0 + 1) * RANK + n];
        #pragma unroll
        for (int r = 0; r < 16; ++r)
            y[r] += sG[r * RANK + k0] * w0 + sG[r * RANK + k0 + 1] * w1;
    }

    float cn = c2[n];
    float w2 = predW2[n];
    #pragma unroll
    for (int r = 0; r < 16; ++r) {
        float h = y[r] + cn;
        if (h < 0.f) h = 0.f;
        sRed[r * RANK + n] = h * w2;
    }
    __syncthreads();
    {
        int r = tid >> 4, j = tid & 15;
        float s = 0.f;
        for (int i = 0; i < 16; ++i) s += sRed[r * RANK + j * 16 + i];
        sQ[r * 16 + j] = s;
    }
    __syncthreads();
    if (tid < 16) {
        float s = 0.f;
        for (int i = 0; i < 16; ++i) s += sQ[tid * 16 + i];
        out[m0 + tid] = s + predB2[0];
    }
}

extern "C" void kernel_launch(void* const* d_in, const int* in_sizes, int n_in,
                              void* d_out, int out_size, void* d_ws, size_t ws_size,
                              hipStream_t stream) {
    const int* features  = (const int*)d_in[0];
    const int* key_ids   = (const int*)d_in[1];
    const int* dd_src    = (const int*)d_in[4];
    const float* emb     = (const float*)d_in[5];
    const float* sageW   = (const float*)d_in[6];
    const float* sageB   = (const float*)d_in[7];
    const float* lnG     = (const float*)d_in[8];
    const float* lnB     = (const float*)d_in[9];
    const float* ddW     = (const float*)d_in[10];
    const float* ddB     = (const float*)d_in[11];
    const float* normG   = (const float*)d_in[12];
    const float* normB   = (const float*)d_in[13];
    const float* infoW   = (const float*)d_in[14];
    const float* infoB   = (const float*)d_in[15];
    const float* aug     = (const float*)d_in[16];
    const float* predW1  = (const float*)d_in[17];
    const float* predB1  = (const float*)d_in[18];
    const float* predW2  = (const float*)d_in[19];
    const float* predB2  = (const float*)d_in[20];

    char* ws = (char*)d_ws;
    float* GE    = (float*)(ws + GE_OFF);
    int*   inv   = (int*)(ws + INV_OFF);
    float* parts = (float*)(ws + PARTS_OFF);
    float* c2    = (float*)(ws + C2_OFF);
    float* outp  = (float*)d_out;

    k_init_inv<<<62, 256, 0, stream>>>(inv);
    k_scatter<<<32, 256, 0, stream>>>(key_ids, inv);
    k_graph_reader<<<NB / 2, 256, 0, stream>>>(features, emb, sageW, sageB, lnG, lnB, GE);
    k_dd_agg<<<32, 256, 0, stream>>>(dd_src, inv, GE, parts);
    k_device<<<1, 256, 0, stream>>>(parts, aug, infoW, infoB, ddW, ddB,
                                    normG, normB, predW1, predB1, c2);
    k_pred<<<NB / 16, 256, 0, stream>>>(GE, predW1, c2, predW2, predB2, outp);
}

// Round 5
// 451.746 us; speedup vs baseline: 1.4116x; 1.4116x over previous
//
#include <hip/hip_runtime.h>

#define RANK 256
#define NB 8192
#define NMAP 15625

typedef unsigned short ushort_t;
typedef short  mfma_ab __attribute__((ext_vector_type(8)));
typedef float  f32x4   __attribute__((ext_vector_type(4)));

// workspace byte offsets (total ~9.6 MB)
#define GEH_OFF   0          // 8192*256 bf16-high = 4,194,304
#define GEL_OFF   4194304    // 8192*256 bf16-low  = 4,194,304
#define WTH_OFF   8388608    // 4 mats * 256*256 bf16 = 524,288
#define WTL_OFF   8912896    // 524,288
#define INV_OFF   9437184    // 15625 int = 62,500
#define PARTS_OFF 9499712    // 32*256 f32 = 32,768
#define C2_OFF    9532480    // 256 f32

__device__ __forceinline__ float b2f(ushort_t u) {
    return __uint_as_float(((unsigned)u) << 16);
}
__device__ __forceinline__ ushort_t f2b(float f) {   // round-to-nearest-even
    unsigned u = __float_as_uint(f);
    return (ushort_t)((u + 0x7FFFu + ((u >> 16) & 1u)) >> 16);
}

__device__ __forceinline__ f32x4 mfma_bf16(mfma_ab a, mfma_ab b, f32x4 c) {
#if defined(__gfx950__)
    return __builtin_amdgcn_mfma_f32_16x16x32_bf16(a, b, c, 0, 0, 0);
#else
    (void)a; (void)b;
    return c;   // never executed on the target device (gfx950)
#endif
}

// ---------------------------------------------------------------- inv = -1
__global__ void k_init_inv(int* inv) {
    int i = blockIdx.x * 256 + threadIdx.x;
    if (i < NMAP) inv[i] = -1;
}

// ------------------------------------------------- inv[key_idx[b]] = b
__global__ void k_scatter(const int* key_ids, int* inv) {
    int b = blockIdx.x * 256 + threadIdx.x;
    const int* kp = key_ids + b * 6;
    int k = kp[0]*3125 + kp[1]*625 + kp[2]*125 + kp[3]*25 + kp[4]*5 + kp[5];
    inv[k] = b;
}

// ---------------- prep: split-transpose weights to [n][k] bf16 hi/lo -------
// 64 blocks: mat = blk>>4 (0..2 sage layers, 3 = predW1 rows 0..255), 16 tiles
__global__ void k_prep_w(const float* __restrict__ sageW,
                         const float* __restrict__ predW1,
                         ushort_t* __restrict__ WTh,
                         ushort_t* __restrict__ WTl)
{
    const int id = blockIdx.x;
    const int mat = id >> 4, tile = id & 15;
    const int tr = tile >> 2, tc = tile & 3;
    const float* src = (mat < 3) ? (sageW + mat * 65536) : predW1;
    ushort_t* dh = WTh + mat * 65536;
    ushort_t* dl = WTl + mat * 65536;
    __shared__ float t[64][65];
    const int tid = threadIdx.x;
    const int c = tid & 63, r0 = tid >> 6;
    #pragma unroll
    for (int i = 0; i < 16; ++i) {
        int r = r0 + i * 4;
        t[r][c] = src[(tr*64 + r) * 256 + tc*64 + c];
    }
    __syncthreads();
    #pragma unroll
    for (int i = 0; i < 16; ++i) {
        int r = r0 + i * 4;
        float f = t[c][r];                       // = src[k = tr*64+c][n = tc*64+r]
        ushort_t h = f2b(f);
        dh[(tc*64 + r) * 256 + tr*64 + c] = h;   // WT[n][k]
        dl[(tc*64 + r) * 256 + tr*64 + c] = f2b(f - b2f(h));
    }
}

// ---------------- fused GraphReader: embed + 3x(SAGE->GEMM->LN->ReLU) ------
// block = 512 threads (8 waves), 5 graphs = 45 rows (pad 48)
// wave w owns output cols [w*32, w*32+32) = 2 N-tiles of 16
#define GR_G 5
#define GR_RPAD 48
#define XP 260   // fp32 activation pitch (260 % 32 == 4 -> 2-way on stores)
#define AP 264   // bf16 split pitch    (132 dw % 32 == 4 -> 2-way on A-frags)

__global__ __launch_bounds__(512, 4) void k_graph_reader(
    const int* __restrict__ features,
    const float* __restrict__ emb,
    const ushort_t* __restrict__ WTh,
    const ushort_t* __restrict__ WTl,
    const float* __restrict__ sageB,
    const float* __restrict__ lnG,
    const float* __restrict__ lnB,
    ushort_t* __restrict__ GEh,
    ushort_t* __restrict__ GEl)
{
    // union: fp32 master [48][260] (49,920 B)  <->  Ah/Al bf16 [48][264] x2 (50,688 B)
    __shared__ __align__(16) char uLDS[50688];
    float*    sXf = (float*)uLDS;
    ushort_t* sAh = (ushort_t*)uLDS;
    ushort_t* sAl = (ushort_t*)(uLDS + 25344);
    __shared__ float2 sPart[GR_RPAD][8];
    __shared__ float2 sMV[GR_RPAD];
    __shared__ int sFeat[GR_RPAD];

    const int tid  = threadIdx.x;
    const int wid  = tid >> 6;
    const int lane = tid & 63;
    const int q4   = lane >> 4;
    const int l15  = lane & 15;
    const int colb = wid * 32;

    const int b0    = blockIdx.x * GR_G;
    const int ngr   = min(GR_G, NB - b0);
    const int nreal = ngr * 9;

    if (tid < GR_RPAD) sFeat[tid] = (tid < nreal) ? features[b0 * 9 + tid] : 0;
    __syncthreads();

    // embed fill: 48 rows x 64 float4 chunks = 3072 tasks = 512*6
    #pragma unroll
    for (int it = 0; it < 6; ++it) {
        int t = tid + it * 512;
        int row = t >> 6, c4 = t & 63;
        if (row < nreal)
            *(float4*)(sXf + row * XP + c4 * 4) =
                *(const float4*)(emb + sFeat[row] * RANK + c4 * 4);
    }

    f32x4 acc[3][2];
    const f32x4 vzero = {0.f, 0.f, 0.f, 0.f};

    for (int L = 0; L < 3; ++L) {
        float bias[2], gv[2], bv[2];
        #pragma unroll
        for (int t = 0; t < 2; ++t) {
            int col = colb + t * 16 + l15;
            bias[t] = sageB[L * RANK + col];
            gv[t]   = lnG[L * RANK + col];
            bv[t]   = lnB[L * RANK + col];
        }
        __syncthreads();   // sXf ready

        // phase 1: chain agg -> registers (fp32)
        float4 a[6];
        #pragma unroll
        for (int it = 0; it < 6; ++it) {
            int t = tid + it * 512;
            int row = t >> 6, c4 = t & 63;
            float4 v = make_float4(0.f, 0.f, 0.f, 0.f);
            if (row < nreal) {
                int j = row % 9;
                v = *(const float4*)(sXf + row * XP + c4 * 4);
                float cnt = 1.f;
                if (j > 0) {
                    float4 u = *(const float4*)(sXf + (row - 1) * XP + c4 * 4);
                    v.x += u.x; v.y += u.y; v.z += u.z; v.w += u.w; cnt += 1.f;
                }
                if (j < 8) {
                    float4 u = *(const float4*)(sXf + (row + 1) * XP + c4 * 4);
                    v.x += u.x; v.y += u.y; v.z += u.z; v.w += u.w; cnt += 1.f;
                }
                float sc = 1.0f / cnt;
                v.x *= sc; v.y *= sc; v.z *= sc; v.w *= sc;
            }
            a[it] = v;
        }
        __syncthreads();   // all sXf reads done -> safe to overwrite w/ splits

        // phase 2: split write Ah/Al (aliases sXf memory)
        #pragma unroll
        for (int it = 0; it < 6; ++it) {
            int t = tid + it * 512;
            int row = t >> 6, c4 = t & 63;
            float4 v = a[it];
            ushort_t h0 = f2b(v.x), h1 = f2b(v.y), h2 = f2b(v.z), h3 = f2b(v.w);
            ushort_t l0 = f2b(v.x - b2f(h0)), l1 = f2b(v.y - b2f(h1));
            ushort_t l2 = f2b(v.z - b2f(h2)), l3 = f2b(v.w - b2f(h3));
            *(uint2*)(sAh + row * AP + c4 * 4) =
                make_uint2((unsigned)h0 | ((unsigned)h1 << 16),
                           (unsigned)h2 | ((unsigned)h3 << 16));
            *(uint2*)(sAl + row * AP + c4 * 4) =
                make_uint2((unsigned)l0 | ((unsigned)l1 << 16),
                           (unsigned)l2 | ((unsigned)l3 << 16));
        }
        __syncthreads();   // Ah/Al ready

        // phase 3: split GEMM  [48 x 256] @ [256 x 256]
        #pragma unroll
        for (int Mt = 0; Mt < 3; ++Mt) { acc[Mt][0] = vzero; acc[Mt][1] = vzero; }
        const ushort_t* bh = WTh + L * 65536 + (colb + l15) * RANK + q4 * 8;
        const ushort_t* bl = WTl + L * 65536 + (colb + l15) * RANK + q4 * 8;
        #pragma unroll
        for (int ks = 0; ks < 8; ++ks) {
            mfma_ab B0h = *(const mfma_ab*)(bh + ks * 32);
            mfma_ab B0l = *(const mfma_ab*)(bl + ks * 32);
            mfma_ab B1h = *(const mfma_ab*)(bh + 16 * RANK + ks * 32);
            mfma_ab B1l = *(const mfma_ab*)(bl + 16 * RANK + ks * 32);
            #pragma unroll
            for (int Mt = 0; Mt < 3; ++Mt) {
                int ao = (Mt * 16 + l15) * AP + ks * 32 + q4 * 8;
                mfma_ab Ah = *(const mfma_ab*)(sAh + ao);
                mfma_ab Al = *(const mfma_ab*)(sAl + ao);
                acc[Mt][0] = mfma_bf16(Ah, B0h, acc[Mt][0]);
                acc[Mt][0] = mfma_bf16(Al, B0h, acc[Mt][0]);
                acc[Mt][0] = mfma_bf16(Ah, B0l, acc[Mt][0]);
                acc[Mt][1] = mfma_bf16(Ah, B1h, acc[Mt][1]);
                acc[Mt][1] = mfma_bf16(Al, B1h, acc[Mt][1]);
                acc[Mt][1] = mfma_bf16(Ah, B1l, acc[Mt][1]);
            }
        }

        // phase 4: bias + LN partials (C-layout: col = lane&15, row = q4*4+q)
        #pragma unroll
        for (int Mt = 0; Mt < 3; ++Mt) {
            #pragma unroll
            for (int q = 0; q < 4; ++q) {
                acc[Mt][0][q] += bias[0];
                acc[Mt][1][q] += bias[1];
                float s  = acc[Mt][0][q] + acc[Mt][1][q];
                float ss = acc[Mt][0][q] * acc[Mt][0][q] + acc[Mt][1][q] * acc[Mt][1][q];
                #pragma unroll
                for (int mask = 1; mask <= 8; mask <<= 1) {
                    s  += __shfl_xor(s, mask, 64);
                    ss += __shfl_xor(ss, mask, 64);
                }
                if (l15 == 0) sPart[Mt * 16 + q4 * 4 + q][wid] = make_float2(s, ss);
            }
        }
        __syncthreads();

        if (tid < GR_RPAD) {
            float s = 0.f, q = 0.f;
            #pragma unroll
            for (int w = 0; w < 8; ++w) { float2 p = sPart[tid][w]; s += p.x; q += p.y; }
            float m = s * (1.0f / 256.0f);
            float var = q * (1.0f / 256.0f) - m * m;
            if (var < 0.f) var = 0.f;
            sMV[tid] = make_float2(m, rsqrtf(var + 1e-5f));
        }
        __syncthreads();

        // phase 5: normalize + ReLU; write fp32 master (or GE split on L==2)
        #pragma unroll
        for (int Mt = 0; Mt < 3; ++Mt) {
            #pragma unroll
            for (int q = 0; q < 4; ++q) {
                int row = Mt * 16 + q4 * 4 + q;
                float2 mr = sMV[row];
                #pragma unroll
                for (int t = 0; t < 2; ++t) {
                    int col = colb + t * 16 + l15;
                    float v = (acc[Mt][t][q] - mr.x) * mr.y * gv[t] + bv[t];
                    v = fmaxf(v, 0.f);
                    if (L < 2) {
                        sXf[row * XP + col] = v;
                    } else if (row < nreal && (row % 9) == 0) {
                        int gi = row / 9;
                        ushort_t h = f2b(v);
                        GEh[(b0 + gi) * RANK + col] = h;
                        GEl[(b0 + gi) * RANK + col] = f2b(v - b2f(h));
                    }
                }
            }
        }
    }
}

// ---------------- dd aggregation partials (deterministic) ------------------
__global__ void k_dd_agg(const int* __restrict__ dd_src,
                         const int* __restrict__ inv,
                         const ushort_t* __restrict__ GEh,
                         const ushort_t* __restrict__ GEl,
                         float* __restrict__ parts)
{
    const int c  = threadIdx.x;
    const int e0 = blockIdx.x * 64;
    float s = 0.f;
    for (int e = e0; e < e0 + 64; ++e) {
        int b = inv[dd_src[e]];
        if (b >= 0) s += b2f(GEh[b * RANK + c]) + b2f(GEl[b * RANK + c]);
    }
    parts[blockIdx.x * RANK + c] = s;
}

// ---------------- device-node vector path -> c2 ----------------------------
__global__ void k_device(const float* __restrict__ parts,
                         const float* __restrict__ aug,
                         const float* __restrict__ infoW,
                         const float* __restrict__ infoB,
                         const float* __restrict__ ddW,
                         const float* __restrict__ ddB,
                         const float* __restrict__ normG,
                         const float* __restrict__ normB,
                         const float* __restrict__ predW1,
                         const float* __restrict__ predB1,
                         float* __restrict__ c2)
{
    __shared__ float sh[RANK];
    __shared__ float sdev[RANK];
    __shared__ float sred[RANK];
    const int n = threadIdx.x;

    float agg = 0.f;
    for (int p = 0; p < 32; ++p) agg += parts[p * RANK + n];
    float info = infoB[n];
    for (int j = 0; j < 5; ++j) info += aug[j] * infoW[j * RANK + n];
    sh[n] = (agg + info) * (1.0f / 2049.0f);   // (agg + self) / (deg + 1)
    __syncthreads();

    float y = ddB[n];
    for (int k = 0; k < RANK; ++k) y += sh[k] * ddW[k * RANK + n];

    sred[n] = y; __syncthreads();
    for (int off = 128; off > 0; off >>= 1) {
        if (n < off) sred[n] += sred[n + off];
        __syncthreads();
    }
    float s = sred[0]; __syncthreads();
    sred[n] = y * y; __syncthreads();
    for (int off = 128; off > 0; off >>= 1) {
        if (n < off) sred[n] += sred[n + off];
        __syncthreads();
    }
    float q = sred[0]; __syncthreads();

    float m = s * (1.0f / 256.0f);
    float var = q * (1.0f / 256.0f) - m * m;
    if (var < 0.f) var = 0.f;
    float rs = rsqrtf(var + 1e-5f);
    float dev = (y - m) * rs * normG[n] + normB[n];
    if (dev < 0.f) dev = 0.f;
    sdev[n] = dev;
    __syncthreads();

    float o = predB1[n];
    for (int k = 0; k < RANK; ++k) o += sdev[k] * predW1[(RANK + k) * RANK + n];
    c2[n] = o;
}

// ---------------- final: out = relu(GE @ W1a + c2) . W2 + b2 ---------------
// block = 64 threads (1 wave) = 16 rows; split MFMA over full N=256
__global__ void k_pred(const ushort_t* __restrict__ GEh,
                       const ushort_t* __restrict__ GEl,
                       const ushort_t* __restrict__ W1h,   // [n][k] hi
                       const ushort_t* __restrict__ W1l,   // [n][k] lo
                       const float* __restrict__ c2,
                       const float* __restrict__ predW2,
                       const float* __restrict__ predB2,
                       float* __restrict__ out)
{
    const int lane = threadIdx.x;
    const int q4 = lane >> 4, l15 = lane & 15;
    const int m0 = blockIdx.x * 16;

    f32x4 acc[16];
    const f32x4 vzero = {0.f, 0.f, 0.f, 0.f};
    #pragma unroll
    for (int Nt = 0; Nt < 16; ++Nt) acc[Nt] = vzero;

    const ushort_t* ah = GEh + (m0 + l15) * RANK + q4 * 8;
    const ushort_t* al = GEl + (m0 + l15) * RANK + q4 * 8;
    const ushort_t* bh = W1h + l15 * RANK + q4 * 8;
    const ushort_t* bl = W1l + l15 * RANK + q4 * 8;
    #pragma unroll
    for (int ks = 0; ks < 8; ++ks) {
        mfma_ab Ah = *(const mfma_ab*)(ah + ks * 32);
        mfma_ab Al = *(const mfma_ab*)(al + ks * 32);
        #pragma unroll
        for (int Nt = 0; Nt < 16; ++Nt) {
            mfma_ab Bh = *(const mfma_ab*)(bh + Nt * 16 * RANK + ks * 32);
            mfma_ab Bl = *(const mfma_ab*)(bl + Nt * 16 * RANK + ks * 32);
            acc[Nt] = mfma_bf16(Ah, Bh, acc[Nt]);
            acc[Nt] = mfma_bf16(Al, Bh, acc[Nt]);
            acc[Nt] = mfma_bf16(Ah, Bl, acc[Nt]);
        }
    }

    float op[4] = {0.f, 0.f, 0.f, 0.f};
    #pragma unroll
    for (int Nt = 0; Nt < 16; ++Nt) {
        int col = Nt * 16 + l15;
        float c2v = c2[col];
        float w2v = predW2[col];
        #pragma unroll
        for (int q = 0; q < 4; ++q) {
            float h = acc[Nt][q] + c2v;
            if (h < 0.f) h = 0.f;
            op[q] += h * w2v;
        }
    }
    #pragma unroll
    for (int mask = 1; mask <= 8; mask <<= 1) {
        #pragma unroll
        for (int q = 0; q < 4; ++q) op[q] += __shfl_xor(op[q], mask, 64);
    }
    if (l15 == 0) {
        float b2 = predB2[0];
        #pragma unroll
        for (int q = 0; q < 4; ++q) out[m0 + q4 * 4 + q] = op[q] + b2;
    }
}

extern "C" void kernel_launch(void* const* d_in, const int* in_sizes, int n_in,
                              void* d_out, int out_size, void* d_ws, size_t ws_size,
                              hipStream_t stream) {
    const int* features  = (const int*)d_in[0];
    const int* key_ids   = (const int*)d_in[1];
    const int* dd_src    = (const int*)d_in[4];
    const float* emb     = (const float*)d_in[5];
    const float* sageW   = (const float*)d_in[6];
    const float* sageB   = (const float*)d_in[7];
    const float* lnG     = (const float*)d_in[8];
    const float* lnB     = (const float*)d_in[9];
    const float* ddW     = (const float*)d_in[10];
    const float* ddB     = (const float*)d_in[11];
    const float* normG   = (const float*)d_in[12];
    const float* normB   = (const float*)d_in[13];
    const float* infoW   = (const float*)d_in[14];
    const float* infoB   = (const float*)d_in[15];
    const float* aug     = (const float*)d_in[16];
    const float* predW1  = (const float*)d_in[17];
    const float* predB1  = (const float*)d_in[18];
    const float* predW2  = (const float*)d_in[19];
    const float* predB2  = (const float*)d_in[20];

    char* ws = (char*)d_ws;
    ushort_t* GEh   = (ushort_t*)(ws + GEH_OFF);
    ushort_t* GEl   = (ushort_t*)(ws + GEL_OFF);
    ushort_t* WTh   = (ushort_t*)(ws + WTH_OFF);
    ushort_t* WTl   = (ushort_t*)(ws + WTL_OFF);
    int*      inv   = (int*)(ws + INV_OFF);
    float*    parts = (float*)(ws + PARTS_OFF);
    float*    c2    = (float*)(ws + C2_OFF);
    float*    outp  = (float*)d_out;

    k_init_inv<<<62, 256, 0, stream>>>(inv);
    k_scatter<<<32, 256, 0, stream>>>(key_ids, inv);
    k_prep_w<<<64, 256, 0, stream>>>(sageW, predW1, WTh, WTl);
    k_graph_reader<<<(NB + GR_G - 1) / GR_G, 512, 0, stream>>>(
        features, emb, WTh, WTl, sageB, lnG, lnB, GEh, GEl);
    k_dd_agg<<<32, 256, 0, stream>>>(dd_src, inv, GEh, GEl, parts);
    k_device<<<1, 256, 0, stream>>>(parts, aug, infoW, infoB, ddW, ddB,
                                    normG, normB, predW1, predB1, c2);
    k_pred<<<NB / 16, 64, 0, stream>>>(GEh, GEl, WTh + 3 * 65536, WTl + 3 * 65536,
                                       c2, predW2, predB2, outp);
}

// Round 6
// 437.808 us; speedup vs baseline: 1.4565x; 1.0318x over previous
//
#include <hip/hip_runtime.h>

#define RANK 256
#define NB 8192
#define NMAP 15625

typedef unsigned short ushort_t;
typedef short  mfma_ab __attribute__((ext_vector_type(8)));
typedef float  f32x4   __attribute__((ext_vector_type(4)));

// workspace byte offsets (total ~9.63 MB)
#define GEH_OFF   0          // 8192*256 bf16-high = 4,194,304
#define GEL_OFF   4194304    // 8192*256 bf16-low  = 4,194,304
#define WTH_OFF   8388608    // 4 mats * 256*256 bf16 = 524,288
#define WTL_OFF   8912896    // 524,288
#define INV_OFF   9437184    // 15625 int = 62,500
#define PARTS_OFF 9499712    // 128*256 f32 = 131,072
#define C2_OFF    9630784    // 256 f32

#define DD_BLOCKS 128        // edges per block = 2048 / 128 = 16

__device__ __forceinline__ float b2f(ushort_t u) {
    return __uint_as_float(((unsigned)u) << 16);
}
__device__ __forceinline__ ushort_t f2b(float f) {   // round-to-nearest-even
    unsigned u = __float_as_uint(f);
    return (ushort_t)((u + 0x7FFFu + ((u >> 16) & 1u)) >> 16);
}

__device__ __forceinline__ f32x4 mfma_bf16(mfma_ab a, mfma_ab b, f32x4 c) {
#if defined(__gfx950__)
    return __builtin_amdgcn_mfma_f32_16x16x32_bf16(a, b, c, 0, 0, 0);
#else
    (void)a; (void)b;
    return c;   // never executed on the target device (gfx950)
#endif
}

// ---------------------------------------------------------------- inv = -1
__global__ void k_init_inv(int* inv) {
    int i = blockIdx.x * 256 + threadIdx.x;
    if (i < NMAP) inv[i] = -1;
}

// ------------------------------------------------- inv[key_idx[b]] = b
__global__ void k_scatter(const int* key_ids, int* inv) {
    int b = blockIdx.x * 256 + threadIdx.x;
    const int* kp = key_ids + b * 6;
    int k = kp[0]*3125 + kp[1]*625 + kp[2]*125 + kp[3]*25 + kp[4]*5 + kp[5];
    inv[k] = b;
}

// ---------------- prep: split-transpose weights to [n][k] bf16 hi/lo -------
__global__ void k_prep_w(const float* __restrict__ sageW,
                         const float* __restrict__ predW1,
                         ushort_t* __restrict__ WTh,
                         ushort_t* __restrict__ WTl)
{
    const int id = blockIdx.x;
    const int mat = id >> 4, tile = id & 15;
    const int tr = tile >> 2, tc = tile & 3;
    const float* src = (mat < 3) ? (sageW + mat * 65536) : predW1;
    ushort_t* dh = WTh + mat * 65536;
    ushort_t* dl = WTl + mat * 65536;
    __shared__ float t[64][65];
    const int tid = threadIdx.x;
    const int c = tid & 63, r0 = tid >> 6;
    #pragma unroll
    for (int i = 0; i < 16; ++i) {
        int r = r0 + i * 4;
        t[r][c] = src[(tr*64 + r) * 256 + tc*64 + c];
    }
    __syncthreads();
    #pragma unroll
    for (int i = 0; i < 16; ++i) {
        int r = r0 + i * 4;
        float f = t[c][r];                       // = src[k = tr*64+c][n = tc*64+r]
        ushort_t h = f2b(f);
        dh[(tc*64 + r) * 256 + tr*64 + c] = h;   // WT[n][k]
        dl[(tc*64 + r) * 256 + tr*64 + c] = f2b(f - b2f(h));
    }
}

// ---------------- fused GraphReader: embed + 3x(SAGE->GEMM->LN->ReLU) ------
// block = 512 threads (8 waves), 5 graphs = 45 rows (pad 48)
// wave w owns output cols [w*32, w*32+32) = 2 N-tiles of 16
#define GR_G 5
#define GR_RPAD 48
#define XP 260   // fp32 activation pitch
#define AP 264   // bf16 split pitch

// LDS caps occupancy at 2 blocks/CU = 4 waves/EU; pin waves_per_eu to 4 so
// the register allocator uses the full 128-VGPR budget instead of spilling
// the a[6] staging array to scratch (round-5: 277 MB WRITE_SIZE of spills).
__global__ __attribute__((amdgpu_flat_work_group_size(512, 512), amdgpu_waves_per_eu(4, 4)))
void k_graph_reader(
    const int* __restrict__ features,
    const float* __restrict__ emb,
    const ushort_t* __restrict__ WTh,
    const ushort_t* __restrict__ WTl,
    const float* __restrict__ sageB,
    const float* __restrict__ lnG,
    const float* __restrict__ lnB,
    ushort_t* __restrict__ GEh,
    ushort_t* __restrict__ GEl)
{
    // union: fp32 master [48][260] (49,920 B)  <->  Ah/Al bf16 [48][264] x2 (50,688 B)
    __shared__ __align__(16) char uLDS[50688];
    float*    sXf = (float*)uLDS;
    ushort_t* sAh = (ushort_t*)uLDS;
    ushort_t* sAl = (ushort_t*)(uLDS + 25344);
    __shared__ float2 sPart[GR_RPAD][8];
    __shared__ float2 sMV[GR_RPAD];
    __shared__ int sFeat[GR_RPAD];

    const int tid  = threadIdx.x;
    const int wid  = tid >> 6;
    const int lane = tid & 63;
    const int q4   = lane >> 4;
    const int l15  = lane & 15;
    const int colb = wid * 32;

    const int b0    = blockIdx.x * GR_G;
    const int ngr   = min(GR_G, NB - b0);
    const int nreal = ngr * 9;

    if (tid < GR_RPAD) sFeat[tid] = (tid < nreal) ? features[b0 * 9 + tid] : 0;
    __syncthreads();

    // embed fill: 48 rows x 64 float4 chunks = 3072 tasks = 512*6
    #pragma unroll
    for (int it = 0; it < 6; ++it) {
        int t = tid + it * 512;
        int row = t >> 6, c4 = t & 63;
        if (row < nreal)
            *(float4*)(sXf + row * XP + c4 * 4) =
                *(const float4*)(emb + sFeat[row] * RANK + c4 * 4);
    }

    f32x4 acc[3][2];
    const f32x4 vzero = {0.f, 0.f, 0.f, 0.f};

    for (int L = 0; L < 3; ++L) {
        float bias[2], gv[2], bv[2];
        #pragma unroll
        for (int t = 0; t < 2; ++t) {
            int col = colb + t * 16 + l15;
            bias[t] = sageB[L * RANK + col];
            gv[t]   = lnG[L * RANK + col];
            bv[t]   = lnB[L * RANK + col];
        }
        __syncthreads();   // sXf ready

        // phase 1: chain agg -> registers (fp32)
        float4 a[6];
        #pragma unroll
        for (int it = 0; it < 6; ++it) {
            int t = tid + it * 512;
            int row = t >> 6, c4 = t & 63;
            float4 v = make_float4(0.f, 0.f, 0.f, 0.f);
            if (row < nreal) {
                int j = row % 9;
                v = *(const float4*)(sXf + row * XP + c4 * 4);
                float cnt = 1.f;
                if (j > 0) {
                    float4 u = *(const float4*)(sXf + (row - 1) * XP + c4 * 4);
                    v.x += u.x; v.y += u.y; v.z += u.z; v.w += u.w; cnt += 1.f;
                }
                if (j < 8) {
                    float4 u = *(const float4*)(sXf + (row + 1) * XP + c4 * 4);
                    v.x += u.x; v.y += u.y; v.z += u.z; v.w += u.w; cnt += 1.f;
                }
                float sc = 1.0f / cnt;
                v.x *= sc; v.y *= sc; v.z *= sc; v.w *= sc;
            }
            a[it] = v;
        }
        __syncthreads();   // all sXf reads done -> safe to overwrite w/ splits

        // phase 2: split write Ah/Al (aliases sXf memory)
        #pragma unroll
        for (int it = 0; it < 6; ++it) {
            int t = tid + it * 512;
            int row = t >> 6, c4 = t & 63;
            float4 v = a[it];
            ushort_t h0 = f2b(v.x), h1 = f2b(v.y), h2 = f2b(v.z), h3 = f2b(v.w);
            ushort_t l0 = f2b(v.x - b2f(h0)), l1 = f2b(v.y - b2f(h1));
            ushort_t l2 = f2b(v.z - b2f(h2)), l3 = f2b(v.w - b2f(h3));
            *(uint2*)(sAh + row * AP + c4 * 4) =
                make_uint2((unsigned)h0 | ((unsigned)h1 << 16),
                           (unsigned)h2 | ((unsigned)h3 << 16));
            *(uint2*)(sAl + row * AP + c4 * 4) =
                make_uint2((unsigned)l0 | ((unsigned)l1 << 16),
                           (unsigned)l2 | ((unsigned)l3 << 16));
        }
        __syncthreads();   // Ah/Al ready

        // phase 3: split GEMM  [48 x 256] @ [256 x 256]
        #pragma unroll
        for (int Mt = 0; Mt < 3; ++Mt) { acc[Mt][0] = vzero; acc[Mt][1] = vzero; }
        const ushort_t* bh = WTh + L * 65536 + (colb + l15) * RANK + q4 * 8;
        const ushort_t* bl = WTl + L * 65536 + (colb + l15) * RANK + q4 * 8;
        #pragma unroll
        for (int ks = 0; ks < 8; ++ks) {
            mfma_ab B0h = *(const mfma_ab*)(bh + ks * 32);
            mfma_ab B0l = *(const mfma_ab*)(bl + ks * 32);
            mfma_ab B1h = *(const mfma_ab*)(bh + 16 * RANK + ks * 32);
            mfma_ab B1l = *(const mfma_ab*)(bl + 16 * RANK + ks * 32);
            #pragma unroll
            for (int Mt = 0; Mt < 3; ++Mt) {
                int ao = (Mt * 16 + l15) * AP + ks * 32 + q4 * 8;
                mfma_ab Ah = *(const mfma_ab*)(sAh + ao);
                mfma_ab Al = *(const mfma_ab*)(sAl + ao);
                acc[Mt][0] = mfma_bf16(Ah, B0h, acc[Mt][0]);
                acc[Mt][0] = mfma_bf16(Al, B0h, acc[Mt][0]);
                acc[Mt][0] = mfma_bf16(Ah, B0l, acc[Mt][0]);
                acc[Mt][1] = mfma_bf16(Ah, B1h, acc[Mt][1]);
                acc[Mt][1] = mfma_bf16(Al, B1h, acc[Mt][1]);
                acc[Mt][1] = mfma_bf16(Ah, B1l, acc[Mt][1]);
            }
        }

        // phase 4: bias + LN partials (C-layout: col = lane&15, row = q4*4+q)
        #pragma unroll
        for (int Mt = 0; Mt < 3; ++Mt) {
            #pragma unroll
            for (int q = 0; q < 4; ++q) {
                acc[Mt][0][q] += bias[0];
                acc[Mt][1][q] += bias[1];
                float s  = acc[Mt][0][q] + acc[Mt][1][q];
                float ss = acc[Mt][0][q] * acc[Mt][0][q] + acc[Mt][1][q] * acc[Mt][1][q];
                #pragma unroll
                for (int mask = 1; mask <= 8; mask <<= 1) {
                    s  += __shfl_xor(s, mask, 64);
                    ss += __shfl_xor(ss, mask, 64);
                }
                if (l15 == 0) sPart[Mt * 16 + q4 * 4 + q][wid] = make_float2(s, ss);
            }
        }
        __syncthreads();

        if (tid < GR_RPAD) {
            float s = 0.f, q = 0.f;
            #pragma unroll
            for (int w = 0; w < 8; ++w) { float2 p = sPart[tid][w]; s += p.x; q += p.y; }
            float m = s * (1.0f / 256.0f);
            float var = q * (1.0f / 256.0f) - m * m;
            if (var < 0.f) var = 0.f;
            sMV[tid] = make_float2(m, rsqrtf(var + 1e-5f));
        }
        __syncthreads();

        // phase 5: normalize + ReLU; write fp32 master (or GE split on L==2)
        #pragma unroll
        for (int Mt = 0; Mt < 3; ++Mt) {
            #pragma unroll
            for (int q = 0; q < 4; ++q) {
                int row = Mt * 16 + q4 * 4 + q;
                float2 mr = sMV[row];
                #pragma unroll
                for (int t = 0; t < 2; ++t) {
                    int col = colb + t * 16 + l15;
                    float v = (acc[Mt][t][q] - mr.x) * mr.y * gv[t] + bv[t];
                    v = fmaxf(v, 0.f);
                    if (L < 2) {
                        sXf[row * XP + col] = v;
                    } else if (row < nreal && (row % 9) == 0) {
                        int gi = row / 9;
                        ushort_t h = f2b(v);
                        GEh[(b0 + gi) * RANK + col] = h;
                        GEl[(b0 + gi) * RANK + col] = f2b(v - b2f(h));
                    }
                }
            }
        }
    }
}

// ---------------- dd aggregation partials (deterministic) ------------------
__global__ void k_dd_agg(const int* __restrict__ dd_src,
                         const int* __restrict__ inv,
                         const ushort_t* __restrict__ GEh,
                         const ushort_t* __restrict__ GEl,
                         float* __restrict__ parts)
{
    const int c  = threadIdx.x;
    const int e0 = blockIdx.x * (2048 / DD_BLOCKS);
    float s = 0.f;
    for (int e = e0; e < e0 + (2048 / DD_BLOCKS); ++e) {
        int b = inv[dd_src[e]];
        if (b >= 0) s += b2f(GEh[b * RANK + c]) + b2f(GEl[b * RANK + c]);
    }
    parts[blockIdx.x * RANK + c] = s;
}

// ---------------- device-node vector path -> c2 ----------------------------
__global__ void k_device(const float* __restrict__ parts,
                         const float* __restrict__ aug,
                         const float* __restrict__ infoW,
                         const float* __restrict__ infoB,
                         const float* __restrict__ ddW,
                         const float* __restrict__ ddB,
                         const float* __restrict__ normG,
                         const float* __restrict__ normB,
                         const float* __restrict__ predW1,
                         const float* __restrict__ predB1,
                         float* __restrict__ c2)
{
    __shared__ float sh[RANK];
    __shared__ float sdev[RANK];
    __shared__ float sred[RANK];
    const int n = threadIdx.x;

    float agg = 0.f;
    for (int p = 0; p < DD_BLOCKS; ++p) agg += parts[p * RANK + n];
    float info = infoB[n];
    for (int j = 0; j < 5; ++j) info += aug[j] * infoW[j * RANK + n];
    sh[n] = (agg + info) * (1.0f / 2049.0f);   // (agg + self) / (deg + 1)
    __syncthreads();

    float y = ddB[n];
    for (int k = 0; k < RANK; ++k) y += sh[k] * ddW[k * RANK + n];

    sred[n] = y; __syncthreads();
    for (int off = 128; off > 0; off >>= 1) {
        if (n < off) sred[n] += sred[n + off];
        __syncthreads();
    }
    float s = sred[0]; __syncthreads();
    sred[n] = y * y; __syncthreads();
    for (int off = 128; off > 0; off >>= 1) {
        if (n < off) sred[n] += sred[n + off];
        __syncthreads();
    }
    float q = sred[0]; __syncthreads();

    float m = s * (1.0f / 256.0f);
    float var = q * (1.0f / 256.0f) - m * m;
    if (var < 0.f) var = 0.f;
    float rs = rsqrtf(var + 1e-5f);
    float dev = (y - m) * rs * normG[n] + normB[n];
    if (dev < 0.f) dev = 0.f;
    sdev[n] = dev;
    __syncthreads();

    float o = predB1[n];
    for (int k = 0; k < RANK; ++k) o += sdev[k] * predW1[(RANK + k) * RANK + n];
    c2[n] = o;
}

// ---------------- final: out = relu(GE @ W1a + c2) . W2 + b2 ---------------
// block = 64 threads (1 wave) = 16 rows; split MFMA over full N=256
__global__ void k_pred(const ushort_t* __restrict__ GEh,
                       const ushort_t* __restrict__ GEl,
                       const ushort_t* __restrict__ W1h,   // [n][k] hi
                       const ushort_t* __restrict__ W1l,   // [n][k] lo
                       const float* __restrict__ c2,
                       const float* __restrict__ predW2,
                       const float* __restrict__ predB2,
                       float* __restrict__ out)
{
    const int lane = threadIdx.x;
    const int q4 = lane >> 4, l15 = lane & 15;
    const int m0 = blockIdx.x * 16;

    f32x4 acc[16];
    const f32x4 vzero = {0.f, 0.f, 0.f, 0.f};
    #pragma unroll
    for (int Nt = 0; Nt < 16; ++Nt) acc[Nt] = vzero;

    const ushort_t* ah = GEh + (m0 + l15) * RANK + q4 * 8;
    const ushort_t* al = GEl + (m0 + l15) * RANK + q4 * 8;
    const ushort_t* bh = W1h + l15 * RANK + q4 * 8;
    const ushort_t* bl = W1l + l15 * RANK + q4 * 8;
    #pragma unroll
    for (int ks = 0; ks < 8; ++ks) {
        mfma_ab Ah = *(const mfma_ab*)(ah + ks * 32);
        mfma_ab Al = *(const mfma_ab*)(al + ks * 32);
        #pragma unroll
        for (int Nt = 0; Nt < 16; ++Nt) {
            mfma_ab Bh = *(const mfma_ab*)(bh + Nt * 16 * RANK + ks * 32);
            mfma_ab Bl = *(const mfma_ab*)(bl + Nt * 16 * RANK + ks * 32);
            acc[Nt] = mfma_bf16(Ah, Bh, acc[Nt]);
            acc[Nt] = mfma_bf16(Al, Bh, acc[Nt]);
            acc[Nt] = mfma_bf16(Ah, Bl, acc[Nt]);
        }
    }

    float op[4] = {0.f, 0.f, 0.f, 0.f};
    #pragma unroll
    for (int Nt = 0; Nt < 16; ++Nt) {
        int col = Nt * 16 + l15;
        float c2v = c2[col];
        float w2v = predW2[col];
        #pragma unroll
        for (int q = 0; q < 4; ++q) {
            float h = acc[Nt][q] + c2v;
            if (h < 0.f) h = 0.f;
            op[q] += h * w2v;
        }
    }
    #pragma unroll
    for (int mask = 1; mask <= 8; mask <<= 1) {
        #pragma unroll
        for (int q = 0; q < 4; ++q) op[q] += __shfl_xor(op[q], mask, 64);
    }
    if (l15 == 0) {
        float b2 = predB2[0];
        #pragma unroll
        for (int q = 0; q < 4; ++q) out[m0 + q4 * 4 + q] = op[q] + b2;
    }
}

extern "C" void kernel_launch(void* const* d_in, const int* in_sizes, int n_in,
                              void* d_out, int out_size, void* d_ws, size_t ws_size,
                              hipStream_t stream) {
    const int* features  = (const int*)d_in[0];
    const int* key_ids   = (const int*)d_in[1];
    const int* dd_src    = (const int*)d_in[4];
    const float* emb     = (const float*)d_in[5];
    const float* sageW   = (const float*)d_in[6];
    const float* sageB   = (const float*)d_in[7];
    const float* lnG     = (const float*)d_in[8];
    const float* lnB     = (const float*)d_in[9];
    const float* ddW     = (const float*)d_in[10];
    const float* ddB     = (const float*)d_in[11];
    const float* normG   = (const float*)d_in[12];
    const float* normB   = (const float*)d_in[13];
    const float* infoW   = (const float*)d_in[14];
    const float* infoB   = (const float*)d_in[15];
    const float* aug     = (const float*)d_in[16];
    const float* predW1  = (const float*)d_in[17];
    const float* predB1  = (const float*)d_in[18];
    const float* predW2  = (const float*)d_in[19];
    const float* predB2  = (const float*)d_in[20];

    char* ws = (char*)d_ws;
    ushort_t* GEh   = (ushort_t*)(ws + GEH_OFF);
    ushort_t* GEl   = (ushort_t*)(ws + GEL_OFF);
    ushort_t* WTh   = (ushort_t*)(ws + WTH_OFF);
    ushort_t* WTl   = (ushort_t*)(ws + WTL_OFF);
    int*      inv   = (int*)(ws + INV_OFF);
    float*    parts = (float*)(ws + PARTS_OFF);
    float*    c2    = (float*)(ws + C2_OFF);
    float*    outp  = (float*)d_out;

    k_init_inv<<<62, 256, 0, stream>>>(inv);
    k_scatter<<<32, 256, 0, stream>>>(key_ids, inv);
    k_prep_w<<<64, 256, 0, stream>>>(sageW, predW1, WTh, WTl);
    k_graph_reader<<<(NB + GR_G - 1) / GR_G, 512, 0, stream>>>(
        features, emb, WTh, WTl, sageB, lnG, lnB, GEh, GEl);
    k_dd_agg<<<DD_BLOCKS, 256, 0, stream>>>(dd_src, inv, GEh, GEl, parts);
    k_device<<<1, 256, 0, stream>>>(parts, aug, infoW, infoB, ddW, ddB,
                                    normG, normB, predW1, predB1, c2);
    k_pred<<<NB / 16, 64, 0, stream>>>(GEh, GEl, WTh + 3 * 65536, WTl + 3 * 65536,
                                       c2, predW2, predB2, outp);
}

// Round 7
// 395.082 us; speedup vs baseline: 1.6140x; 1.1081x over previous
//
#include <hip/hip_runtime.h>

#define RANK 256
#define NB 8192
#define NMAP 15625

typedef unsigned short ushort_t;
typedef short  mfma_ab __attribute__((ext_vector_type(8)));
typedef float  f32x4   __attribute__((ext_vector_type(4)));

// workspace byte offsets (total ~9.63 MB)
#define GEH_OFF   0          // 8192*256 bf16-high = 4,194,304
#define GEL_OFF   4194304    // 8192*256 bf16-low  = 4,194,304
#define WTH_OFF   8388608    // 4 mats * 256*256 bf16 = 524,288
#define WTL_OFF   8912896    // 524,288
#define INV_OFF   9437184    // 15625 int = 62,500
#define PARTS_OFF 9499712    // 128*256 f32 = 131,072
#define C2_OFF    9630784    // 256 f32

#define DD_BLOCKS 128        // edges per block = 2048 / 128 = 16

__device__ __forceinline__ float b2f(ushort_t u) {
    return __uint_as_float(((unsigned)u) << 16);
}
__device__ __forceinline__ ushort_t f2b(float f) {   // round-to-nearest-even
    unsigned u = __float_as_uint(f);
    return (ushort_t)((u + 0x7FFFu + ((u >> 16) & 1u)) >> 16);
}

__device__ __forceinline__ f32x4 mfma_bf16(mfma_ab a, mfma_ab b, f32x4 c) {
#if defined(__gfx950__)
    return __builtin_amdgcn_mfma_f32_16x16x32_bf16(a, b, c, 0, 0, 0);
#else
    (void)a; (void)b;
    return c;   // never executed on the target device (gfx950)
#endif
}

// ---------------------------------------------------------------- inv = -1
__global__ void k_init_inv(int* inv) {
    int i = blockIdx.x * 256 + threadIdx.x;
    if (i < NMAP) inv[i] = -1;
}

// ------------------------------------------------- inv[key_idx[b]] = b
__global__ void k_scatter(const int* key_ids, int* inv) {
    int b = blockIdx.x * 256 + threadIdx.x;
    const int* kp = key_ids + b * 6;
    int k = kp[0]*3125 + kp[1]*625 + kp[2]*125 + kp[3]*25 + kp[4]*5 + kp[5];
    inv[k] = b;
}

// ---------------- prep: split-transpose weights to [n][k] bf16 hi/lo -------
__global__ void k_prep_w(const float* __restrict__ sageW,
                         const float* __restrict__ predW1,
                         ushort_t* __restrict__ WTh,
                         ushort_t* __restrict__ WTl)
{
    const int id = blockIdx.x;
    const int mat = id >> 4, tile = id & 15;
    const int tr = tile >> 2, tc = tile & 3;
    const float* src = (mat < 3) ? (sageW + mat * 65536) : predW1;
    ushort_t* dh = WTh + mat * 65536;
    ushort_t* dl = WTl + mat * 65536;
    __shared__ float t[64][65];
    const int tid = threadIdx.x;
    const int c = tid & 63, r0 = tid >> 6;
    #pragma unroll
    for (int i = 0; i < 16; ++i) {
        int r = r0 + i * 4;
        t[r][c] = src[(tr*64 + r) * 256 + tc*64 + c];
    }
    __syncthreads();
    #pragma unroll
    for (int i = 0; i < 16; ++i) {
        int r = r0 + i * 4;
        float f = t[c][r];                       // = src[k = tr*64+c][n = tc*64+r]
        ushort_t h = f2b(f);
        dh[(tc*64 + r) * 256 + tr*64 + c] = h;   // WT[n][k]
        dl[(tc*64 + r) * 256 + tr*64 + c] = f2b(f - b2f(h));
    }
}

// ---------------- fused GraphReader: embed + 3x(SAGE->GEMM->LN->ReLU) ------
// block = 512 threads (8 waves), 5 graphs = 45 rows (pad 48)
// wave w owns output cols [w*32, w*32+32) = 2 N-tiles of 16
#define GR_G 5
#define GR_RPAD 48
#define XP 260   // fp32 activation pitch
#define AP 264   // bf16 split pitch

// Round-6 lesson: per-thread ARRAYS (a[6], acc[3][2]) were lowered to scratch
// (SROA failure) -> 277 MB/dispatch of private-memory spill traffic, VGPR=64.
// Everything below is scalarized into named variables; no local arrays.

#define AGG_LOAD(IT, V)                                                        \
    {                                                                          \
        const int t_ = tid + (IT) * 512;                                       \
        const int row_ = t_ >> 6, c4_ = t_ & 63;                               \
        V = make_float4(0.f, 0.f, 0.f, 0.f);                                   \
        if (row_ < nreal) {                                                    \
            const int j_ = row_ % 9;                                           \
            V = *(const float4*)(sXf + row_ * XP + c4_ * 4);                   \
            float cnt_ = 1.f;                                                  \
            if (j_ > 0) {                                                      \
                float4 u_ = *(const float4*)(sXf + (row_ - 1) * XP + c4_ * 4); \
                V.x += u_.x; V.y += u_.y; V.z += u_.z; V.w += u_.w; cnt_ += 1.f;\
            }                                                                  \
            if (j_ < 8) {                                                      \
                float4 u_ = *(const float4*)(sXf + (row_ + 1) * XP + c4_ * 4); \
                V.x += u_.x; V.y += u_.y; V.z += u_.z; V.w += u_.w; cnt_ += 1.f;\
            }                                                                  \
            const float sc_ = 1.0f / cnt_;                                     \
            V.x *= sc_; V.y *= sc_; V.z *= sc_; V.w *= sc_;                    \
        }                                                                      \
    }

#define AGG_STORE(IT, V)                                                       \
    {                                                                          \
        const int t_ = tid + (IT) * 512;                                       \
        const int row_ = t_ >> 6, c4_ = t_ & 63;                               \
        const ushort_t h0_ = f2b(V.x), h1_ = f2b(V.y);                         \
        const ushort_t h2_ = f2b(V.z), h3_ = f2b(V.w);                         \
        const ushort_t l0_ = f2b(V.x - b2f(h0_)), l1_ = f2b(V.y - b2f(h1_));   \
        const ushort_t l2_ = f2b(V.z - b2f(h2_)), l3_ = f2b(V.w - b2f(h3_));   \
        *(uint2*)(sAh + row_ * AP + c4_ * 4) =                                 \
            make_uint2((unsigned)h0_ | ((unsigned)h1_ << 16),                  \
                       (unsigned)h2_ | ((unsigned)h3_ << 16));                 \
        *(uint2*)(sAl + row_ * AP + c4_ * 4) =                                 \
            make_uint2((unsigned)l0_ | ((unsigned)l1_ << 16),                  \
                       (unsigned)l2_ | ((unsigned)l3_ << 16));                 \
    }

#define LN_PART(ACC0, ACC1, MT)                                                \
    _Pragma("unroll")                                                          \
    for (int q = 0; q < 4; ++q) {                                              \
        ACC0[q] += bias0; ACC1[q] += bias1;                                    \
        float s_  = ACC0[q] + ACC1[q];                                         \
        float ss_ = ACC0[q] * ACC0[q] + ACC1[q] * ACC1[q];                     \
        _Pragma("unroll")                                                      \
        for (int mask = 1; mask <= 8; mask <<= 1) {                            \
            s_  += __shfl_xor(s_, mask, 64);                                   \
            ss_ += __shfl_xor(ss_, mask, 64);                                  \
        }                                                                      \
        if (l15 == 0) sPart[(MT) * 16 + q4 * 4 + q][wid] = make_float2(s_, ss_);\
    }

#define LN_WRITE(ACC0, ACC1, MT)                                               \
    _Pragma("unroll")                                                          \
    for (int q = 0; q < 4; ++q) {                                              \
        const int row_ = (MT) * 16 + q4 * 4 + q;                               \
        const float2 mr_ = sMV[row_];                                          \
        float v0_ = (ACC0[q] - mr_.x) * mr_.y * gv0 + bv0;                     \
        float v1_ = (ACC1[q] - mr_.x) * mr_.y * gv1 + bv1;                     \
        v0_ = fmaxf(v0_, 0.f); v1_ = fmaxf(v1_, 0.f);                          \
        if (L < 2) {                                                           \
            sXf[row_ * XP + colb + l15]      = v0_;                            \
            sXf[row_ * XP + colb + 16 + l15] = v1_;                            \
        } else if (row_ < nreal && (row_ % 9) == 0) {                          \
            const int gi_ = row_ / 9;                                          \
            const ushort_t h0_ = f2b(v0_), h1_ = f2b(v1_);                     \
            GEh[(b0 + gi_) * RANK + colb + l15]      = h0_;                    \
            GEl[(b0 + gi_) * RANK + colb + l15]      = f2b(v0_ - b2f(h0_));    \
            GEh[(b0 + gi_) * RANK + colb + 16 + l15] = h1_;                    \
            GEl[(b0 + gi_) * RANK + colb + 16 + l15] = f2b(v1_ - b2f(h1_));    \
        }                                                                      \
    }

__global__ __launch_bounds__(512, 4) void k_graph_reader(
    const int* __restrict__ features,
    const float* __restrict__ emb,
    const ushort_t* __restrict__ WTh,
    const ushort_t* __restrict__ WTl,
    const float* __restrict__ sageB,
    const float* __restrict__ lnG,
    const float* __restrict__ lnB,
    ushort_t* __restrict__ GEh,
    ushort_t* __restrict__ GEl)
{
    // union: fp32 master [48][260] (49,920 B)  <->  Ah/Al bf16 [48][264] x2 (50,688 B)
    __shared__ __align__(16) char uLDS[50688];
    float*    sXf = (float*)uLDS;
    ushort_t* sAh = (ushort_t*)uLDS;
    ushort_t* sAl = (ushort_t*)(uLDS + 25344);
    __shared__ float2 sPart[GR_RPAD][8];
    __shared__ float2 sMV[GR_RPAD];
    __shared__ int sFeat[GR_RPAD];

    const int tid  = threadIdx.x;
    const int wid  = tid >> 6;
    const int lane = tid & 63;
    const int q4   = lane >> 4;
    const int l15  = lane & 15;
    const int colb = wid * 32;

    const int b0    = blockIdx.x * GR_G;
    const int ngr   = min(GR_G, NB - b0);
    const int nreal = ngr * 9;

    if (tid < GR_RPAD) sFeat[tid] = (tid < nreal) ? features[b0 * 9 + tid] : 0;
    __syncthreads();

    // embed fill: 48 rows x 64 float4 chunks = 3072 tasks = 512*6
    #pragma unroll
    for (int it = 0; it < 6; ++it) {
        int t = tid + it * 512;
        int row = t >> 6, c4 = t & 63;
        if (row < nreal)
            *(float4*)(sXf + row * XP + c4 * 4) =
                *(const float4*)(emb + sFeat[row] * RANK + c4 * 4);
    }

    const f32x4 vzero = {0.f, 0.f, 0.f, 0.f};

    for (int L = 0; L < 3; ++L) {
        float bias0, bias1, gv0, gv1, bv0, bv1;
        {
            int col0 = colb + l15, col1 = colb + 16 + l15;
            bias0 = sageB[L * RANK + col0]; bias1 = sageB[L * RANK + col1];
            gv0   = lnG[L * RANK + col0];   gv1   = lnG[L * RANK + col1];
            bv0   = lnB[L * RANK + col0];   bv1   = lnB[L * RANK + col1];
        }
        __syncthreads();   // sXf ready (embed or previous layer write-back)

        // phase 1: chain agg -> named registers (fp32)
        float4 a0, a1, a2, a3, a4, a5;
        AGG_LOAD(0, a0) AGG_LOAD(1, a1) AGG_LOAD(2, a2)
        AGG_LOAD(3, a3) AGG_LOAD(4, a4) AGG_LOAD(5, a5)
        __syncthreads();   // all sXf reads done -> safe to overwrite w/ splits

        // phase 2: split write Ah/Al (aliases sXf memory)
        AGG_STORE(0, a0) AGG_STORE(1, a1) AGG_STORE(2, a2)
        AGG_STORE(3, a3) AGG_STORE(4, a4) AGG_STORE(5, a5)
        __syncthreads();   // Ah/Al ready

        // phase 3: split GEMM  [48 x 256] @ [256 x 256]
        f32x4 acc00 = vzero, acc01 = vzero;
        f32x4 acc10 = vzero, acc11 = vzero;
        f32x4 acc20 = vzero, acc21 = vzero;
        const ushort_t* bh = WTh + L * 65536 + (colb + l15) * RANK + q4 * 8;
        const ushort_t* bl = WTl + L * 65536 + (colb + l15) * RANK + q4 * 8;
        #pragma unroll
        for (int ks = 0; ks < 8; ++ks) {
            mfma_ab B0h = *(const mfma_ab*)(bh + ks * 32);
            mfma_ab B0l = *(const mfma_ab*)(bl + ks * 32);
            mfma_ab B1h = *(const mfma_ab*)(bh + 16 * RANK + ks * 32);
            mfma_ab B1l = *(const mfma_ab*)(bl + 16 * RANK + ks * 32);
            const int ab = l15 * AP + ks * 32 + q4 * 8;

            mfma_ab A0h = *(const mfma_ab*)(sAh + ab);
            mfma_ab A0l = *(const mfma_ab*)(sAl + ab);
            acc00 = mfma_bf16(A0h, B0h, acc00);
            acc00 = mfma_bf16(A0l, B0h, acc00);
            acc00 = mfma_bf16(A0h, B0l, acc00);
            acc01 = mfma_bf16(A0h, B1h, acc01);
            acc01 = mfma_bf16(A0l, B1h, acc01);
            acc01 = mfma_bf16(A0h, B1l, acc01);

            mfma_ab A1h = *(const mfma_ab*)(sAh + ab + 16 * AP);
            mfma_ab A1l = *(const mfma_ab*)(sAl + ab + 16 * AP);
            acc10 = mfma_bf16(A1h, B0h, acc10);
            acc10 = mfma_bf16(A1l, B0h, acc10);
            acc10 = mfma_bf16(A1h, B0l, acc10);
            acc11 = mfma_bf16(A1h, B1h, acc11);
            acc11 = mfma_bf16(A1l, B1h, acc11);
            acc11 = mfma_bf16(A1h, B1l, acc11);

            mfma_ab A2h = *(const mfma_ab*)(sAh + ab + 32 * AP);
            mfma_ab A2l = *(const mfma_ab*)(sAl + ab + 32 * AP);
            acc20 = mfma_bf16(A2h, B0h, acc20);
            acc20 = mfma_bf16(A2l, B0h, acc20);
            acc20 = mfma_bf16(A2h, B0l, acc20);
            acc21 = mfma_bf16(A2h, B1h, acc21);
            acc21 = mfma_bf16(A2l, B1h, acc21);
            acc21 = mfma_bf16(A2h, B1l, acc21);
        }

        // phase 4: bias + LN partials (C-layout: col = lane&15, row = q4*4+q)
        LN_PART(acc00, acc01, 0)
        LN_PART(acc10, acc11, 1)
        LN_PART(acc20, acc21, 2)
        __syncthreads();

        if (tid < GR_RPAD) {
            float s = 0.f, q = 0.f;
            #pragma unroll
            for (int w = 0; w < 8; ++w) { float2 p = sPart[tid][w]; s += p.x; q += p.y; }
            float m = s * (1.0f / 256.0f);
            float var = q * (1.0f / 256.0f) - m * m;
            if (var < 0.f) var = 0.f;
            sMV[tid] = make_float2(m, rsqrtf(var + 1e-5f));
        }
        __syncthreads();

        // phase 5: normalize + ReLU; write fp32 master (or GE split on L==2)
        LN_WRITE(acc00, acc01, 0)
        LN_WRITE(acc10, acc11, 1)
        LN_WRITE(acc20, acc21, 2)
    }
}

// ---------------- dd aggregation partials (deterministic) ------------------
__global__ void k_dd_agg(const int* __restrict__ dd_src,
                         const int* __restrict__ inv,
                         const ushort_t* __restrict__ GEh,
                         const ushort_t* __restrict__ GEl,
                         float* __restrict__ parts)
{
    const int c  = threadIdx.x;
    const int e0 = blockIdx.x * (2048 / DD_BLOCKS);
    float s = 0.f;
    for (int e = e0; e < e0 + (2048 / DD_BLOCKS); ++e) {
        int b = inv[dd_src[e]];
        if (b >= 0) s += b2f(GEh[b * RANK + c]) + b2f(GEl[b * RANK + c]);
    }
    parts[blockIdx.x * RANK + c] = s;
}

// ---------------- device-node vector path -> c2 ----------------------------
__global__ void k_device(const float* __restrict__ parts,
                         const float* __restrict__ aug,
                         const float* __restrict__ infoW,
                         const float* __restrict__ infoB,
                         const float* __restrict__ ddW,
                         const float* __restrict__ ddB,
                         const float* __restrict__ normG,
                         const float* __restrict__ normB,
                         const float* __restrict__ predW1,
                         const float* __restrict__ predB1,
                         float* __restrict__ c2)
{
    __shared__ float sh[RANK];
    __shared__ float sdev[RANK];
    __shared__ float sred[RANK];
    const int n = threadIdx.x;

    float agg = 0.f;
    for (int p = 0; p < DD_BLOCKS; ++p) agg += parts[p * RANK + n];
    float info = infoB[n];
    for (int j = 0; j < 5; ++j) info += aug[j] * infoW[j * RANK + n];
    sh[n] = (agg + info) * (1.0f / 2049.0f);   // (agg + self) / (deg + 1)
    __syncthreads();

    float y = ddB[n];
    for (int k = 0; k < RANK; ++k) y += sh[k] * ddW[k * RANK + n];

    sred[n] = y; __syncthreads();
    for (int off = 128; off > 0; off >>= 1) {
        if (n < off) sred[n] += sred[n + off];
        __syncthreads();
    }
    float s = sred[0]; __syncthreads();
    sred[n] = y * y; __syncthreads();
    for (int off = 128; off > 0; off >>= 1) {
        if (n < off) sred[n] += sred[n + off];
        __syncthreads();
    }
    float q = sred[0]; __syncthreads();

    float m = s * (1.0f / 256.0f);
    float var = q * (1.0f / 256.0f) - m * m;
    if (var < 0.f) var = 0.f;
    float rs = rsqrtf(var + 1e-5f);
    float dev = (y - m) * rs * normG[n] + normB[n];
    if (dev < 0.f) dev = 0.f;
    sdev[n] = dev;
    __syncthreads();

    float o = predB1[n];
    for (int k = 0; k < RANK; ++k) o += sdev[k] * predW1[(RANK + k) * RANK + n];
    c2[n] = o;
}

// ---------------- final: out = relu(GE @ W1a + c2) . W2 + b2 ---------------
// block = 64 threads (1 wave) = 16 rows; split MFMA over full N=256
__global__ void k_pred(const ushort_t* __restrict__ GEh,
                       const ushort_t* __restrict__ GEl,
                       const ushort_t* __restrict__ W1h,   // [n][k] hi
                       const ushort_t* __restrict__ W1l,   // [n][k] lo
                       const float* __restrict__ c2,
                       const float* __restrict__ predW2,
                       const float* __restrict__ predB2,
                       float* __restrict__ out)
{
    const int lane = threadIdx.x;
    const int q4 = lane >> 4, l15 = lane & 15;
    const int m0 = blockIdx.x * 16;

    f32x4 acc[16];
    const f32x4 vzero = {0.f, 0.f, 0.f, 0.f};
    #pragma unroll
    for (int Nt = 0; Nt < 16; ++Nt) acc[Nt] = vzero;

    const ushort_t* ah = GEh + (m0 + l15) * RANK + q4 * 8;
    const ushort_t* al = GEl + (m0 + l15) * RANK + q4 * 8;
    const ushort_t* bh = W1h + l15 * RANK + q4 * 8;
    const ushort_t* bl = W1l + l15 * RANK + q4 * 8;
    #pragma unroll
    for (int ks = 0; ks < 8; ++ks) {
        mfma_ab Ah = *(const mfma_ab*)(ah + ks * 32);
        mfma_ab Al = *(const mfma_ab*)(al + ks * 32);
        #pragma unroll
        for (int Nt = 0; Nt < 16; ++Nt) {
            mfma_ab Bh = *(const mfma_ab*)(bh + Nt * 16 * RANK + ks * 32);
            mfma_ab Bl = *(const mfma_ab*)(bl + Nt * 16 * RANK + ks * 32);
            acc[Nt] = mfma_bf16(Ah, Bh, acc[Nt]);
            acc[Nt] = mfma_bf16(Al, Bh, acc[Nt]);
            acc[Nt] = mfma_bf16(Ah, Bl, acc[Nt]);
        }
    }

    float op0 = 0.f, op1 = 0.f, op2 = 0.f, op3 = 0.f;
    #pragma unroll
    for (int Nt = 0; Nt < 16; ++Nt) {
        int col = Nt * 16 + l15;
        float c2v = c2[col];
        float w2v = predW2[col];
        float h0 = fmaxf(acc[Nt][0] + c2v, 0.f);
        float h1 = fmaxf(acc[Nt][1] + c2v, 0.f);
        float h2 = fmaxf(acc[Nt][2] + c2v, 0.f);
        float h3 = fmaxf(acc[Nt][3] + c2v, 0.f);
        op0 += h0 * w2v; op1 += h1 * w2v; op2 += h2 * w2v; op3 += h3 * w2v;
    }
    #pragma unroll
    for (int mask = 1; mask <= 8; mask <<= 1) {
        op0 += __shfl_xor(op0, mask, 64);
        op1 += __shfl_xor(op1, mask, 64);
        op2 += __shfl_xor(op2, mask, 64);
        op3 += __shfl_xor(op3, mask, 64);
    }
    if (l15 == 0) {
        float b2 = predB2[0];
        out[m0 + q4 * 4 + 0] = op0 + b2;
        out[m0 + q4 * 4 + 1] = op1 + b2;
        out[m0 + q4 * 4 + 2] = op2 + b2;
        out[m0 + q4 * 4 + 3] = op3 + b2;
    }
}

extern "C" void kernel_launch(void* const* d_in, const int* in_sizes, int n_in,
                              void* d_out, int out_size, void* d_ws, size_t ws_size,
                              hipStream_t stream) {
    const int* features  = (const int*)d_in[0];
    const int* key_ids   = (const int*)d_in[1];
    const int* dd_src    = (const int*)d_in[4];
    const float* emb     = (const float*)d_in[5];
    const float* sageW   = (const float*)d_in[6];
    const float* sageB   = (const float*)d_in[7];
    const float* lnG     = (const float*)d_in[8];
    const float* lnB     = (const float*)d_in[9];
    const float* ddW     = (const float*)d_in[10];
    const float* ddB     = (const float*)d_in[11];
    const float* normG   = (const float*)d_in[12];
    const float* normB   = (const float*)d_in[13];
    const float* infoW   = (const float*)d_in[14];
    const float* infoB   = (const float*)d_in[15];
    const float* aug     = (const float*)d_in[16];
    const float* predW1  = (const float*)d_in[17];
    const float* predB1  = (const float*)d_in[18];
    const float* predW2  = (const float*)d_in[19];
    const float* predB2  = (const float*)d_in[20];

    char* ws = (char*)d_ws;
    ushort_t* GEh   = (ushort_t*)(ws + GEH_OFF);
    ushort_t* GEl   = (ushort_t*)(ws + GEL_OFF);
    ushort_t* WTh   = (ushort_t*)(ws + WTH_OFF);
    ushort_t* WTl   = (ushort_t*)(ws + WTL_OFF);
    int*      inv   = (int*)(ws + INV_OFF);
    float*    parts = (float*)(ws + PARTS_OFF);
    float*    c2    = (float*)(ws + C2_OFF);
    float*    outp  = (float*)d_out;

    k_init_inv<<<62, 256, 0, stream>>>(inv);
    k_scatter<<<32, 256, 0, stream>>>(key_ids, inv);
    k_prep_w<<<64, 256, 0, stream>>>(sageW, predW1, WTh, WTl);
    k_graph_reader<<<(NB + GR_G - 1) / GR_G, 512, 0, stream>>>(
        features, emb, WTh, WTl, sageB, lnG, lnB, GEh, GEl);
    k_dd_agg<<<DD_BLOCKS, 256, 0, stream>>>(dd_src, inv, GEh, GEl, parts);
    k_device<<<1, 256, 0, stream>>>(parts, aug, infoW, infoB, ddW, ddB,
                                    normG, normB, predW1, predB1, c2);
    k_pred<<<NB / 16, 64, 0, stream>>>(GEh, GEl, WTh + 3 * 65536, WTl + 3 * 65536,
                                       c2, predW2, predB2, outp);
}